// Round 1
// baseline (283.396 us; speedup 1.0000x reference)
//
#include <hip/hip_runtime.h>
#include <math.h>

#define DD 128
#define HH 256
#define WW 256
#define HWS (HH*WW)
#define VOL (DD*HH*WW)
#define TH 16
#define TW 64
#define DC 32
#define SH (TH+4)
#define SW (TW+4)
#define MH (TH+2)
#define MW (TW+2)
#define NT 256

__device__ __forceinline__ int slot3(int s) { return ((s % 3) + 3) % 3; }

__global__ __launch_bounds__(NT) void skel_reduce_kernel(
    const float* __restrict__ y_pred, const float* __restrict__ y_true,
    double* __restrict__ acc)
{
  __shared__ float IMG[SH][SW];      // staged img slice, halo 2, OOB=+inf
  __shared__ float Mb[3][MH][MW];    // rolling 2D-min slices
  __shared__ float ER[MH][MW];       // eroded slice (core+halo1), OOB=-inf
  __shared__ float Ab[3][TH][TW];    // rolling 2D-max(eroded) slices
  __shared__ float IC[3][TH][TW];    // rolling img core slices
  __shared__ float red[2][NT/64];

  const int bid = blockIdx.x;
  const int wt = bid & 3;          // 4 W tiles
  const int ht = (bid >> 2) & 15;  // 16 H tiles
  const int dt = (bid >> 6) & 3;   // 4 D chunks
  const int v  = bid >> 8;         // 0..3 : role*2 + b
  const int role = v >> 1;         // 0: skeletonize y_pred, 1: skeletonize y_true
  const int b = v & 1;

  const float* img   = (role == 0 ? y_pred : y_true) + (size_t)b * VOL;
  const float* other = (role == 0 ? y_true : y_pred) + (size_t)b * VOL;

  const int h0 = ht * TH, w0 = wt * TW, d0 = dt * DC;
  const int tid = threadIdx.x;

  // ---- phase lambdas ------------------------------------------------------
  auto stage = [&](int s) {               // global -> IMG (before barrier)
    if (s < 0 || s >= DD) return;
    const float* src = img + (size_t)s * HWS;
    for (int i = tid; i < SH*SW; i += NT) {
      int r = i / SW, c = i - r*SW;
      int gh = h0 - 2 + r, gw = w0 - 2 + c;
      float val = INFINITY;               // erosion pads with +inf (ignored)
      if (gh >= 0 && gh < HH && gw >= 0 && gw < WW)
        val = src[gh*WW + gw];
      IMG[r][c] = val;
    }
  };

  auto m2phase = [&](int s) {             // IMG -> Mb[slot], IC[slot]
    int sl = slot3(s);
    if (s < 0 || s >= DD) {
      for (int i = tid; i < MH*MW; i += NT) {
        int r = i / MW, c = i - r*MW;
        Mb[sl][r][c] = INFINITY;
      }
      return;
    }
    for (int i = tid; i < MH*MW; i += NT) {
      int r = i / MW, c = i - r*MW;
      float m =        IMG[r  ][c];
      m = fminf(m, IMG[r  ][c+1]); m = fminf(m, IMG[r  ][c+2]);
      m = fminf(m, IMG[r+1][c]);   m = fminf(m, IMG[r+1][c+1]); m = fminf(m, IMG[r+1][c+2]);
      m = fminf(m, IMG[r+2][c]);   m = fminf(m, IMG[r+2][c+1]); m = fminf(m, IMG[r+2][c+2]);
      Mb[sl][r][c] = m;
    }
    for (int i = tid; i < TH*TW; i += NT) {
      int r = i >> 6, c = i & 63;
      IC[sl][r][c] = IMG[r+2][c+2];
    }
  };

  auto erphase = [&](int e) {             // Mb x3 -> ER  (mask OOB h/w = -inf)
    if (e < 0 || e >= DD) return;
    int sm = slot3(e-1), s0 = slot3(e), sp = slot3(e+1);
    for (int i = tid; i < MH*MW; i += NT) {
      int r = i / MW, c = i - r*MW;
      float val = fminf(fminf(Mb[sm][r][c], Mb[s0][r][c]), Mb[sp][r][c]);
      int gh = h0 - 1 + r, gw = w0 - 1 + c;
      if (gh < 0 || gh >= HH || gw < 0 || gw >= WW) val = -INFINITY;
      ER[r][c] = val;
    }
  };

  auto a2phase = [&](int e) {             // ER -> Ab[slot]
    int sl = slot3(e);
    if (e < 0 || e >= DD) {
      for (int i = tid; i < TH*TW; i += NT) {
        int r = i >> 6, c = i & 63;
        Ab[sl][r][c] = -INFINITY;         // dilation pads with -inf (ignored)
      }
      return;
    }
    for (int i = tid; i < TH*TW; i += NT) {
      int r = i >> 6, c = i & 63;
      float m =        ER[r  ][c];
      m = fmaxf(m, ER[r  ][c+1]); m = fmaxf(m, ER[r  ][c+2]);
      m = fmaxf(m, ER[r+1][c]);   m = fmaxf(m, ER[r+1][c+1]); m = fmaxf(m, ER[r+1][c+2]);
      m = fmaxf(m, ER[r+2][c]);   m = fmaxf(m, ER[r+2][c+1]); m = fmaxf(m, ER[r+2][c+2]);
      Ab[sl][r][c] = m;
    }
  };

  float accN = 0.f, accD = 0.f;

  auto outphase = [&](int d) {            // opened -> skel -> fused reduce
    int am = slot3(d-1), a0 = slot3(d), ap = slot3(d+1);
    int r = tid >> 4, c4 = (tid & 15) << 2;   // 16 rows x 16 col-groups of 4
    const float4 o4 = *reinterpret_cast<const float4*>(
        other + (size_t)d*HWS + (size_t)(h0+r)*WW + (w0+c4));
    float4 A0 = *reinterpret_cast<const float4*>(&Ab[am][r][c4]);
    float4 A1 = *reinterpret_cast<const float4*>(&Ab[a0][r][c4]);
    float4 A2 = *reinterpret_cast<const float4*>(&Ab[ap][r][c4]);
    float4 I4 = *reinterpret_cast<const float4*>(&IC[a0][r][c4]);
    float s0 = fmaxf(I4.x - fmaxf(fmaxf(A0.x, A1.x), A2.x), 0.f);
    float s1 = fmaxf(I4.y - fmaxf(fmaxf(A0.y, A1.y), A2.y), 0.f);
    float s2 = fmaxf(I4.z - fmaxf(fmaxf(A0.z, A1.z), A2.z), 0.f);
    float s3 = fmaxf(I4.w - fmaxf(fmaxf(A0.w, A1.w), A2.w), 0.f);
    accN += s0*o4.x + s1*o4.y + s2*o4.z + s3*o4.w;
    accD += s0 + s1 + s2 + s3;
  };

  // ---- pipeline prologue --------------------------------------------------
  stage(d0-2); __syncthreads(); m2phase(d0-2); __syncthreads();
  stage(d0-1); __syncthreads(); m2phase(d0-1); __syncthreads();
  stage(d0  ); __syncthreads(); m2phase(d0  ); __syncthreads();
  erphase(d0-1); __syncthreads(); a2phase(d0-1); __syncthreads();
  stage(d0+1); __syncthreads(); m2phase(d0+1); __syncthreads();
  erphase(d0  ); __syncthreads(); a2phase(d0  ); __syncthreads();

  // ---- main loop: 4 barriers / iteration ---------------------------------
  for (int d = d0; d < d0 + DC; ++d) {
    stage(d+2);                 __syncthreads();
    m2phase(d+2);               __syncthreads();
    erphase(d+1);               __syncthreads();
    a2phase(d+1);               __syncthreads();
    outphase(d);
    // no barrier needed: next writes that touch what outphase read are
    // separated by >=1 barrier (stage only writes IMG).
  }

  // ---- block reduction ----------------------------------------------------
  for (int off = 32; off > 0; off >>= 1) {
    accN += __shfl_down(accN, off);
    accD += __shfl_down(accD, off);
  }
  int wave = tid >> 6, lane = tid & 63;
  if (lane == 0) { red[0][wave] = accN; red[1][wave] = accD; }
  __syncthreads();
  if (tid == 0) {
    float n  = red[0][0] + red[0][1] + red[0][2] + red[0][3];
    float dn = red[1][0] + red[1][1] + red[1][2] + red[1][3];
    atomicAdd(&acc[v*2 + 0], (double)n);
    atomicAdd(&acc[v*2 + 1], (double)dn);
  }
}

__global__ void finalize_kernel(const double* __restrict__ acc,
                                float* __restrict__ out)
{
  const double smooth = 1e-5;
  double cl[2];
  for (int b = 0; b < 2; ++b) {
    double tprec = acc[(0*2+b)*2 + 0] / (acc[(0*2+b)*2 + 1] + smooth);
    double tsens = acc[(1*2+b)*2 + 0] / (acc[(1*2+b)*2 + 1] + smooth);
    cl[b] = 2.0 * tprec * tsens / (tprec + tsens + smooth);
  }
  out[0] = (float)(1.0 - 0.5*(cl[0] + cl[1]));
}

extern "C" void kernel_launch(void* const* d_in, const int* in_sizes, int n_in,
                              void* d_out, int out_size, void* d_ws, size_t ws_size,
                              hipStream_t stream) {
  const float* y_pred = (const float*)d_in[0];
  const float* y_true = (const float*)d_in[1];
  double* acc = (double*)d_ws;
  hipMemsetAsync(d_ws, 0, 8*sizeof(double), stream);
  // 4 volumes (role x batch) * 4 D-chunks * 16 H-tiles * 4 W-tiles = 1024 blocks
  skel_reduce_kernel<<<dim3(1024), dim3(NT), 0, stream>>>(y_pred, y_true, acc);
  finalize_kernel<<<dim3(1), dim3(1), 0, stream>>>(acc, (float*)d_out);
}

// Round 2
// 149.206 us; speedup vs baseline: 1.8994x; 1.8994x over previous
//
#include <hip/hip_runtime.h>
#include <math.h>

#define DD 128
#define HH 256
#define WW 256
#define HWS (HH*WW)
#define VOL (DD*HH*WW)
#define TH 16
#define TW 64
#define DC 16           // D-chunk per block -> 8 chunks
#define SH 20           // TH+4
#define SW 72           // TW+4 padded to 72 floats (288B rows, 16B-aligned)
#define MH 18           // er rows (TH+2)
#define MWU 17          // er col-groups of 4 (covers 68 cols; 66 needed)
#define ERW 68          // er row stride (272B, 16B-aligned)
#define NT 256
#define NUNIT (MH*MWU)  // 306 m2-units

__global__ __launch_bounds__(NT) void skel_reduce_kernel(
    const float* __restrict__ y_pred, const float* __restrict__ y_true,
    double* __restrict__ acc)
{
  __shared__ alignas(16) float IMG[SH][SW];   // staged slice, OOB=+inf
  __shared__ alignas(16) float ER[MH][ERW];   // eroded slice, OOB(h,w)=-inf
  __shared__ float red[2][NT/64];

  const int bid = blockIdx.x;
  const int wt = bid & 3;           // 4 W tiles
  const int ht = (bid >> 2) & 15;   // 16 H tiles
  const int dt = (bid >> 6) & 7;    // 8 D chunks
  const int v  = bid >> 9;          // 0..3 : role*2 + batch
  const int role = v >> 1;          // 0: skeletonize y_pred, 1: y_true
  const int b = v & 1;

  const float* img   = (role == 0 ? y_pred : y_true) + (size_t)b * VOL;
  const float* other = (role == 0 ? y_true : y_pred) + (size_t)b * VOL;

  const int h0 = ht * TH, w0 = wt * TW, d0 = dt * DC;
  const int tid = threadIdx.x;

  // ---- per-thread m2/er unit precompute (2 units of 4 cols) --------------
  int u_imgoff[2], u_eroff[2];
  unsigned u_mask[2];   // bit j: er output col j is inside the volume
  bool u_valid[2];
  #pragma unroll
  for (int k = 0; k < 2; ++k) {
    int u = tid + k * NT;
    u_valid[k] = (u < NUNIT);
    int uu = u_valid[k] ? u : 0;
    int row = uu / MWU;
    int cg  = uu - row * MWU;
    int c   = cg << 2;
    u_imgoff[k] = row * SW + c;     // IMG window top-left (rows row..row+2, cols c..c+5)
    u_eroff[k]  = row * ERW + c;
    int ghE = h0 - 1 + row;
    unsigned m = 0;
    if ((unsigned)ghE < HH) {
      #pragma unroll
      for (int j = 0; j < 4; ++j) {
        int gwE = w0 - 1 + c + j;
        if ((unsigned)gwE < WW) m |= (1u << j);
      }
    }
    u_mask[k] = m;
  }

  // ---- a2/out ownership: row ar, cols ac..ac+3 ---------------------------
  const int ar = tid >> 4;            // 0..15
  const int ac = (tid & 15) << 2;     // 0..60
  const int a_eroff  = ar * ERW + ac;       // ER window rows ar..ar+2, cols ac..ac+5
  const int a_imgoff = (ar + 2) * SW + (ac + 2);  // img core in IMG

  // ---- rolling registers (static indices only) ---------------------------
  float m2_p2[2][4], m2_p1[2][4], m2_c[2][4];
  float a2_p2[4], a2_p1[4], a2_c[4];
  float ic_p2[4], ic_p1[4], ic_c[4];
  #pragma unroll
  for (int k = 0; k < 2; ++k)
    #pragma unroll
    for (int j = 0; j < 4; ++j) { m2_p2[k][j] = INFINITY; m2_p1[k][j] = INFINITY; }
  #pragma unroll
  for (int j = 0; j < 4; ++j) {
    a2_p2[j] = -INFINITY; a2_p1[j] = -INFINITY;
    ic_p2[j] = 0.f; ic_p1[j] = 0.f; ic_c[j] = 0.f;
  }

  float accN = 0.f, accD = 0.f;

  // ---- pipeline: step S stages slice S, computes er(S-1), outputs d=S-2 --
  for (int S = d0 - 2; S <= d0 + DC + 1; ++S) {
    const bool inS = (S >= 0 && S < DD);
    // phase 1: stage slice S -> IMG
    if (inS) {
      const float* src = img + (size_t)S * HWS;
      #pragma unroll
      for (int it = 0; it < 6; ++it) {
        int i = tid + it * NT;
        if (i < SH * SW) {
          int r = i / SW, c = i - r * SW;
          int gh = h0 - 2 + r, gw = w0 - 2 + c;
          float val = INFINITY;
          if ((unsigned)gh < HH && (unsigned)gw < WW) val = src[gh * WW + gw];
          IMG[r][c] = val;
        }
      }
    }
    __syncthreads();

    // phase 2: 2D-min (regs), img core (regs), er(S-1) -> ER
    #pragma unroll
    for (int k = 0; k < 2; ++k) {
      if (inS && u_valid[k]) {
        const float* base = &IMG[0][0] + u_imgoff[k];
        float cm0 = INFINITY, cm1 = INFINITY, cm2 = INFINITY,
              cm3 = INFINITY, cm4 = INFINITY, cm5 = INFINITY;
        #pragma unroll
        for (int rr = 0; rr < 3; ++rr) {
          const float* rp = base + rr * SW;
          float4 v4 = *reinterpret_cast<const float4*>(rp);
          float2 v2 = *reinterpret_cast<const float2*>(rp + 4);
          cm0 = fminf(cm0, v4.x); cm1 = fminf(cm1, v4.y);
          cm2 = fminf(cm2, v4.z); cm3 = fminf(cm3, v4.w);
          cm4 = fminf(cm4, v2.x); cm5 = fminf(cm5, v2.y);
        }
        m2_c[k][0] = fminf(fminf(cm0, cm1), cm2);
        m2_c[k][1] = fminf(fminf(cm1, cm2), cm3);
        m2_c[k][2] = fminf(fminf(cm2, cm3), cm4);
        m2_c[k][3] = fminf(fminf(cm3, cm4), cm5);
      } else {
        #pragma unroll
        for (int j = 0; j < 4; ++j) m2_c[k][j] = INFINITY;
      }
    }
    if (inS) {
      float2 i2a = *reinterpret_cast<const float2*>(&IMG[0][0] + a_imgoff);
      float2 i2b = *reinterpret_cast<const float2*>(&IMG[0][0] + a_imgoff + 2);
      ic_c[0] = i2a.x; ic_c[1] = i2a.y; ic_c[2] = i2b.x; ic_c[3] = i2b.y;
    } else {
      #pragma unroll
      for (int j = 0; j < 4; ++j) ic_c[j] = 0.f;
    }
    #pragma unroll
    for (int k = 0; k < 2; ++k) {
      if (u_valid[k]) {
        float4 e4;
        float e0 = fminf(fminf(m2_p2[k][0], m2_p1[k][0]), m2_c[k][0]);
        float e1 = fminf(fminf(m2_p2[k][1], m2_p1[k][1]), m2_c[k][1]);
        float e2 = fminf(fminf(m2_p2[k][2], m2_p1[k][2]), m2_c[k][2]);
        float e3 = fminf(fminf(m2_p2[k][3], m2_p1[k][3]), m2_c[k][3]);
        e4.x = (u_mask[k] & 1u) ? e0 : -INFINITY;
        e4.y = (u_mask[k] & 2u) ? e1 : -INFINITY;
        e4.z = (u_mask[k] & 4u) ? e2 : -INFINITY;
        e4.w = (u_mask[k] & 8u) ? e3 : -INFINITY;
        *reinterpret_cast<float4*>(&ER[0][0] + u_eroff[k]) = e4;
      }
    }
    __syncthreads();

    // phase 3: 2D-max of ER (regs), opened(d=S-2), skel, fused reduce
    const int e = S - 1;
    if (e >= 0 && e < DD) {
      float cx0 = -INFINITY, cx1 = -INFINITY, cx2 = -INFINITY,
            cx3 = -INFINITY, cx4 = -INFINITY, cx5 = -INFINITY;
      const float* ebase = &ER[0][0] + a_eroff;
      #pragma unroll
      for (int rr = 0; rr < 3; ++rr) {
        const float* rp = ebase + rr * ERW;
        float4 v4 = *reinterpret_cast<const float4*>(rp);
        float2 v2 = *reinterpret_cast<const float2*>(rp + 4);
        cx0 = fmaxf(cx0, v4.x); cx1 = fmaxf(cx1, v4.y);
        cx2 = fmaxf(cx2, v4.z); cx3 = fmaxf(cx3, v4.w);
        cx4 = fmaxf(cx4, v2.x); cx5 = fmaxf(cx5, v2.y);
      }
      a2_c[0] = fmaxf(fmaxf(cx0, cx1), cx2);
      a2_c[1] = fmaxf(fmaxf(cx1, cx2), cx3);
      a2_c[2] = fmaxf(fmaxf(cx2, cx3), cx4);
      a2_c[3] = fmaxf(fmaxf(cx3, cx4), cx5);
    } else {
      #pragma unroll
      for (int j = 0; j < 4; ++j) a2_c[j] = -INFINITY;
    }

    const int d = S - 2;
    if (d >= d0) {  // d < d0+DC guaranteed by loop bound
      float4 o4 = *reinterpret_cast<const float4*>(
          other + (size_t)d * HWS + (size_t)(h0 + ar) * WW + (w0 + ac));
      #pragma unroll
      for (int j = 0; j < 4; ++j) {
        float opened = fmaxf(fmaxf(a2_p2[j], a2_p1[j]), a2_c[j]);
        float s = fmaxf(ic_p2[j] - opened, 0.f);
        accN += s * (&o4.x)[j];
        accD += s;
      }
    }

    // shift rolling registers
    #pragma unroll
    for (int k = 0; k < 2; ++k)
      #pragma unroll
      for (int j = 0; j < 4; ++j) {
        m2_p2[k][j] = m2_p1[k][j]; m2_p1[k][j] = m2_c[k][j];
      }
    #pragma unroll
    for (int j = 0; j < 4; ++j) {
      a2_p2[j] = a2_p1[j]; a2_p1[j] = a2_c[j];
      ic_p2[j] = ic_p1[j]; ic_p1[j] = ic_c[j];
    }
  }

  // ---- block reduction ----------------------------------------------------
  for (int off = 32; off > 0; off >>= 1) {
    accN += __shfl_down(accN, off);
    accD += __shfl_down(accD, off);
  }
  int wave = tid >> 6, lane = tid & 63;
  if (lane == 0) { red[0][wave] = accN; red[1][wave] = accD; }
  __syncthreads();
  if (tid == 0) {
    float n  = red[0][0] + red[0][1] + red[0][2] + red[0][3];
    float dn = red[1][0] + red[1][1] + red[1][2] + red[1][3];
    atomicAdd(&acc[v * 2 + 0], (double)n);
    atomicAdd(&acc[v * 2 + 1], (double)dn);
  }
}

__global__ void finalize_kernel(const double* __restrict__ acc,
                                float* __restrict__ out)
{
  const double smooth = 1e-5;
  double cl[2];
  for (int b = 0; b < 2; ++b) {
    double tprec = acc[(0 * 2 + b) * 2 + 0] / (acc[(0 * 2 + b) * 2 + 1] + smooth);
    double tsens = acc[(1 * 2 + b) * 2 + 0] / (acc[(1 * 2 + b) * 2 + 1] + smooth);
    cl[b] = 2.0 * tprec * tsens / (tprec + tsens + smooth);
  }
  out[0] = (float)(1.0 - 0.5 * (cl[0] + cl[1]));
}

extern "C" void kernel_launch(void* const* d_in, const int* in_sizes, int n_in,
                              void* d_out, int out_size, void* d_ws, size_t ws_size,
                              hipStream_t stream) {
  const float* y_pred = (const float*)d_in[0];
  const float* y_true = (const float*)d_in[1];
  double* acc = (double*)d_ws;
  hipMemsetAsync(d_ws, 0, 8 * sizeof(double), stream);
  // 4 volumes (role x batch) * 8 D-chunks * 16 H-tiles * 4 W-tiles = 2048 blocks
  skel_reduce_kernel<<<dim3(2048), dim3(NT), 0, stream>>>(y_pred, y_true, acc);
  finalize_kernel<<<dim3(1), dim3(1), 0, stream>>>(acc, (float*)d_out);
}

// Round 3
// 127.328 us; speedup vs baseline: 2.2257x; 1.1718x over previous
//
#include <hip/hip_runtime.h>
#include <math.h>

#define DD 128
#define HH 256
#define WWD 256
#define HWS (HH*WWD)
#define VOL (DD*HWS)
#define DC 16
#define NT 256

// per-wave tile
#define TH 16
#define TW 16
#define SH 20
#define SW 20      // IMG row stride (floats)
#define EH 18
#define EW 20      // ER row stride (floats)
#define IMGSZ (SH*SW)   // 400
#define ERSZ  (EH*EW)   // 360

#define FINF (__builtin_inff())

// Stage slice SLICE (global, +inf-padded at h/w borders) into DSTBUF (wave-private).
#define STAGE(SLICE, DSTBUF) do {                                              \
    int _s = (SLICE);                                                          \
    if (_s >= 0 && _s < DD) {                                                  \
      const float* _sp = img + (size_t)_s * HWS;                               \
      _Pragma("unroll")                                                        \
      for (int _it = 0; _it < 4; ++_it) {                                      \
        if (stw[_it]) {                                                        \
          float2 _x = *reinterpret_cast<const float2*>(_sp + stoff[_it]);      \
          _x.x = fmaxf(_x.x, smask[_it]);                                      \
          _x.y = fmaxf(_x.y, smask[_it]);                                      \
          *reinterpret_cast<float2*>((DSTBUF) + 2*(lane + _it*64)) = _x;       \
        }                                                                      \
      }                                                                        \
    }                                                                          \
  } while (0)

// One pipeline step. P = t%3 (register window phase), B = t&1 (LDS buffer).
// step t: stage slice d0-1+t -> buf B; m2+ic of slice d0-2+t from buf B^1;
//         er/a2 of slice d0-3+t via buf B of ER; out d0-4+t.
#define STEP(T, P, B) do {                                                     \
    const int t_  = (T);                                                       \
    const int Sst = d0 - 1 + t_;                                               \
    const int Sm  = d0 - 2 + t_;                                               \
    const int Se  = d0 - 3 + t_;                                               \
    const int dd  = d0 - 4 + t_;                                               \
    constexpr int Pm1 = ((P) + 2) % 3, Pm2 = ((P) + 1) % 3;                    \
    float*       imgW = (B) ? imgBuf1 : imgBuf0;                               \
    const float* imgR = (B) ? imgBuf0 : imgBuf1;                               \
    float*       erB  = (B) ? erBuf1  : erBuf0;                                \
    /* prefetch 'other' for the output slice */                                \
    float4 o4 = make_float4(0.f, 0.f, 0.f, 0.f);                               \
    const bool douts = (t_ >= 4);                                              \
    if (douts)                                                                 \
      o4 = *reinterpret_cast<const float4*>(other + (size_t)dd*HWS + ooff);    \
    /* stage next slice */                                                     \
    if (t_ <= DC + 2) STAGE(Sst, imgW);                                        \
    /* 2D-min (m2) + img-core of slice Sm from previous-step buffer */         \
    if (Sm >= 0 && Sm < DD) {                                                  \
      _Pragma("unroll")                                                        \
      for (int k2 = 0; k2 < 2; ++k2) {                                         \
        const float* bp = imgR + m2off[k2];                                    \
        float4 r0a = *reinterpret_cast<const float4*>(bp);                     \
        float2 r0b = *reinterpret_cast<const float2*>(bp + 4);                 \
        float4 r1a = *reinterpret_cast<const float4*>(bp + SW);                \
        float2 r1b = *reinterpret_cast<const float2*>(bp + SW + 4);            \
        float4 r2a = *reinterpret_cast<const float4*>(bp + 2*SW);              \
        float2 r2b = *reinterpret_cast<const float2*>(bp + 2*SW + 4);          \
        float c0 = fminf(fminf(r0a.x, r1a.x), r2a.x);                          \
        float c1 = fminf(fminf(r0a.y, r1a.y), r2a.y);                          \
        float c2 = fminf(fminf(r0a.z, r1a.z), r2a.z);                          \
        float c3 = fminf(fminf(r0a.w, r1a.w), r2a.w);                          \
        float c4 = fminf(fminf(r0b.x, r1b.x), r2b.x);                          \
        float c5 = fminf(fminf(r0b.y, r1b.y), r2b.y);                          \
        m2w[P][k2][0] = fminf(fminf(c0, c1), c2);                              \
        m2w[P][k2][1] = fminf(fminf(c1, c2), c3);                              \
        m2w[P][k2][2] = fminf(fminf(c2, c3), c4);                              \
        m2w[P][k2][3] = fminf(fminf(c3, c4), c5);                              \
      }                                                                        \
      float2 ica = *reinterpret_cast<const float2*>(imgR + icoff);             \
      float2 icb = *reinterpret_cast<const float2*>(imgR + icoff + 2);         \
      icw[P][0] = ica.x; icw[P][1] = ica.y;                                    \
      icw[P][2] = icb.x; icw[P][3] = icb.y;                                    \
    } else {                                                                   \
      _Pragma("unroll")                                                        \
      for (int k2 = 0; k2 < 2; ++k2)                                           \
        { m2w[P][k2][0] = FINF; m2w[P][k2][1] = FINF;                          \
          m2w[P][k2][2] = FINF; m2w[P][k2][3] = FINF; }                        \
      icw[P][0] = 0.f; icw[P][1] = 0.f; icw[P][2] = 0.f; icw[P][3] = 0.f;      \
    }                                                                          \
    /* erosion slice Se -> ER buf (masked to -inf at volume borders), then */  \
    /* 2D-max (a2) of the same slice (same-step LDS round-trip, wave-local) */ \
    if (Se >= 0 && Se < DD) {                                                  \
      _Pragma("unroll")                                                        \
      for (int k2 = 0; k2 < 2; ++k2) {                                         \
        if (m2v[k2]) {                                                         \
          float4 e;                                                            \
          e.x = fminf(fminf(fminf(m2w[P][k2][0], m2w[Pm1][k2][0]),             \
                            m2w[Pm2][k2][0]), ermask[k2][0]);                  \
          e.y = fminf(fminf(fminf(m2w[P][k2][1], m2w[Pm1][k2][1]),             \
                            m2w[Pm2][k2][1]), ermask[k2][1]);                  \
          e.z = fminf(fminf(fminf(m2w[P][k2][2], m2w[Pm1][k2][2]),             \
                            m2w[Pm2][k2][2]), ermask[k2][2]);                  \
          e.w = fminf(fminf(fminf(m2w[P][k2][3], m2w[Pm1][k2][3]),             \
                            m2w[Pm2][k2][3]), ermask[k2][3]);                  \
          *reinterpret_cast<float4*>(erB + m2off[k2]) = e;                     \
        }                                                                      \
      }                                                                        \
      const float* ep = erB + a2off;                                           \
      float4 q0a = *reinterpret_cast<const float4*>(ep);                       \
      float2 q0b = *reinterpret_cast<const float2*>(ep + 4);                   \
      float4 q1a = *reinterpret_cast<const float4*>(ep + EW);                  \
      float2 q1b = *reinterpret_cast<const float2*>(ep + EW + 4);              \
      float4 q2a = *reinterpret_cast<const float4*>(ep + 2*EW);                \
      float2 q2b = *reinterpret_cast<const float2*>(ep + 2*EW + 4);            \
      float x0 = fmaxf(fmaxf(q0a.x, q1a.x), q2a.x);                            \
      float x1 = fmaxf(fmaxf(q0a.y, q1a.y), q2a.y);                            \
      float x2 = fmaxf(fmaxf(q0a.z, q1a.z), q2a.z);                            \
      float x3 = fmaxf(fmaxf(q0a.w, q1a.w), q2a.w);                            \
      float x4 = fmaxf(fmaxf(q0b.x, q1b.x), q2b.x);                            \
      float x5 = fmaxf(fmaxf(q0b.y, q1b.y), q2b.y);                            \
      a2w[P][0] = fmaxf(fmaxf(x0, x1), x2);                                    \
      a2w[P][1] = fmaxf(fmaxf(x1, x2), x3);                                    \
      a2w[P][2] = fmaxf(fmaxf(x2, x3), x4);                                    \
      a2w[P][3] = fmaxf(fmaxf(x3, x4), x5);                                    \
    } else {                                                                   \
      a2w[P][0] = -FINF; a2w[P][1] = -FINF;                                    \
      a2w[P][2] = -FINF; a2w[P][3] = -FINF;                                    \
    }                                                                          \
    /* output slice dd: opened = max3 over a2 window; skel; fused reduce */    \
    if (douts) {                                                               \
      _Pragma("unroll")                                                        \
      for (int j = 0; j < 4; ++j) {                                            \
        float op = fmaxf(fmaxf(a2w[P][j], a2w[Pm1][j]), a2w[Pm2][j]);          \
        float s  = fmaxf(icw[Pm2][j] - op, 0.f);                               \
        accN += s * (&o4.x)[j];                                                \
        accD += s;                                                             \
      }                                                                        \
    }                                                                          \
  } while (0)

__global__ __launch_bounds__(NT, 4) void skel_reduce_kernel(
    const float* __restrict__ y_pred, const float* __restrict__ y_true,
    double* __restrict__ acc)
{
  __shared__ alignas(16) float LIMG[4][2][IMGSZ];
  __shared__ alignas(16) float LER [4][2][ERSZ];
  __shared__ float red[2][4];

  const int tid  = threadIdx.x;
  const int wid  = tid >> 6;
  const int lane = tid & 63;
  const int gwv  = blockIdx.x * 4 + wid;   // global wave id, 0..8191
  const int wt = gwv & 15;
  const int ht = (gwv >> 4) & 15;
  const int dt = (gwv >> 8) & 7;
  const int v  = gwv >> 11;                // block-uniform (2048 | 4*bid)
  const int role = v >> 1, b = v & 1;

  const float* img   = (role == 0 ? y_pred : y_true) + (size_t)b * VOL;
  const float* other = (role == 0 ? y_true : y_pred) + (size_t)b * VOL;

  const int h0 = ht * TH, w0 = wt * TW, d0 = dt * DC;

  // ---- staging setup: 200 float2 units over IMG[20][20] ----
  int stoff[4]; float smask[4]; bool stw[4];
  #pragma unroll
  for (int it = 0; it < 4; ++it) {
    int u = lane + it * 64;
    bool inU = (u < 200);
    int uu = inU ? u : 0;
    int r = uu / 10, c2 = uu - 10 * r;
    int gh = h0 - 2 + r, gw = w0 - 2 + 2 * c2;
    bool valid = inU && (unsigned)gh < HH && gw >= 0 && gw <= (WWD - 2);
    stoff[it] = valid ? (gh * WWD + gw) : 0;
    smask[it] = valid ? -FINF : FINF;   // fmaxf(x, -inf)=x ; fmaxf(x,+inf)=+inf
    stw[it]   = inU;
  }

  // ---- m2/er units: 90 units of (1 row x 4 cols) over ER[18][18..20] ----
  int m2off[2]; float ermask[2][4]; bool m2v[2];
  #pragma unroll
  for (int k2 = 0; k2 < 2; ++k2) {
    int u = lane + 64 * k2;
    bool vu = (u < 90);
    int uu = vu ? u : 0;
    int row = uu / 5, g = uu - 5 * row;
    m2off[k2] = row * SW + 4 * g;
    m2v[k2] = vu;
    int ghE = h0 - 1 + row;
    #pragma unroll
    for (int j = 0; j < 4; ++j) {
      int cc  = 4 * g + j;
      int gwE = w0 - 1 + cc;
      bool ok = vu && (unsigned)ghE < HH && (unsigned)gwE < WWD && cc <= 17;
      ermask[k2][j] = ok ? FINF : -FINF;  // fminf(e,+inf)=e ; fminf(e,-inf)=-inf
    }
  }

  // ---- a2/out ownership: 1 row x 4 cols of the 16x16 core per lane ----
  const int ar = lane >> 2, ag = lane & 3;
  const int a2off = ar * EW + 4 * ag;
  const int icoff = (ar + 2) * SW + 4 * ag + 2;
  const size_t ooff = (size_t)(h0 + ar) * WWD + (w0 + 4 * ag);

  // ---- rolling register windows (all indices compile-time) ----
  float m2w[3][2][4], a2w[3][4], icw[3][4];
  #pragma unroll
  for (int p = 0; p < 3; ++p) {
    #pragma unroll
    for (int k2 = 0; k2 < 2; ++k2)
      #pragma unroll
      for (int j = 0; j < 4; ++j) m2w[p][k2][j] = FINF;
    #pragma unroll
    for (int j = 0; j < 4; ++j) { a2w[p][j] = -FINF; icw[p][j] = 0.f; }
  }
  float accN = 0.f, accD = 0.f;

  float* const imgBuf0 = &LIMG[wid][0][0];
  float* const imgBuf1 = &LIMG[wid][1][0];
  float* const erBuf0  = &LER[wid][0][0];
  float* const erBuf1  = &LER[wid][1][0];

  // ---- prologue: prestage slice d0-2 into buf1 (read by step 0) ----
  STAGE(d0 - 2, imgBuf1);

  // ---- 20 barrier-free pipeline steps (unroll 6 keeps P/B constant) ----
  for (int tb = 0; tb < 18; tb += 6) {
    STEP(tb + 0, 0, 0);
    STEP(tb + 1, 1, 1);
    STEP(tb + 2, 2, 0);
    STEP(tb + 3, 0, 1);
    STEP(tb + 4, 1, 0);
    STEP(tb + 5, 2, 1);
  }
  STEP(18, 0, 0);
  STEP(19, 1, 1);

  // ---- reduction: wave shuffle -> LDS -> one atomic pair per block ----
  #pragma unroll
  for (int off = 32; off > 0; off >>= 1) {
    accN += __shfl_down(accN, off);
    accD += __shfl_down(accD, off);
  }
  if (lane == 0) { red[0][wid] = accN; red[1][wid] = accD; }
  __syncthreads();
  if (tid == 0) {
    float n  = red[0][0] + red[0][1] + red[0][2] + red[0][3];
    float dn = red[1][0] + red[1][1] + red[1][2] + red[1][3];
    atomicAdd(&acc[v * 2 + 0], (double)n);
    atomicAdd(&acc[v * 2 + 1], (double)dn);
  }
}

__global__ void finalize_kernel(const double* __restrict__ acc,
                                float* __restrict__ out)
{
  const double smooth = 1e-5;
  double cl[2];
  for (int b = 0; b < 2; ++b) {
    double tprec = acc[(0 * 2 + b) * 2 + 0] / (acc[(0 * 2 + b) * 2 + 1] + smooth);
    double tsens = acc[(1 * 2 + b) * 2 + 0] / (acc[(1 * 2 + b) * 2 + 1] + smooth);
    cl[b] = 2.0 * tprec * tsens / (tprec + tsens + smooth);
  }
  out[0] = (float)(1.0 - 0.5 * (cl[0] + cl[1]));
}

extern "C" void kernel_launch(void* const* d_in, const int* in_sizes, int n_in,
                              void* d_out, int out_size, void* d_ws, size_t ws_size,
                              hipStream_t stream) {
  const float* y_pred = (const float*)d_in[0];
  const float* y_true = (const float*)d_in[1];
  double* acc = (double*)d_ws;
  hipMemsetAsync(d_ws, 0, 8 * sizeof(double), stream);
  // 8192 independent waves: 4 volumes x 8 D-chunks x 16 ht x 16 wt -> 2048 blocks
  skel_reduce_kernel<<<dim3(2048), dim3(NT), 0, stream>>>(y_pred, y_true, acc);
  finalize_kernel<<<dim3(1), dim3(1), 0, stream>>>(acc, (float*)d_out);
}

// Round 5
// 67.481 us; speedup vs baseline: 4.1997x; 1.8869x over previous
//
#include <hip/hip_runtime.h>
#include <math.h>

#define DD 128
#define HH 256
#define WD 256
#define HWS (HH*WD)
#define VOLS ((size_t)DD*HWS)
#define DC 16          // slices per wave-tile -> 8 d-chunks
#define NT 256
#define FINF (__builtin_inff())

__device__ __forceinline__ float min3f(float a, float b, float c) {
  return fminf(fminf(a, b), c);   // fuses to v_min3_f32
}
__device__ __forceinline__ float max3f(float a, float b, float c) {
  return fmaxf(fmaxf(a, b), c);   // fuses to v_max3_f32
}

#define MIN3V(d,a,b,c) do{ (d).x=min3f((a).x,(b).x,(c).x); (d).y=min3f((a).y,(b).y,(c).y); \
                           (d).z=min3f((a).z,(b).z,(c).z); (d).w=min3f((a).w,(b).w,(c).w);}while(0)
#define MAX3V(d,a,b,c) do{ (d).x=max3f((a).x,(b).x,(c).x); (d).y=max3f((a).y,(b).y,(c).y); \
                           (d).z=max3f((a).z,(b).z,(c).z); (d).w=max3f((a).w,(b).w,(c).w);}while(0)
#define SET4(d,val)    do{ (d).x=(val); (d).y=(val); (d).z=(val); (d).w=(val);}while(0)

// One pipeline step for staged slice zS = (SARG).
// NOTE: all macro-local names are z*/vv-prefixed to avoid shadowing the
// caller's variables (R4 failed on `const int S = (S);` self-init).
// Writes m2(zS) into M2WR (parity array of zS), mx(zS-1) into MXWR (parity
// of zS-1). Emits skel output for slice zo = zS-2 when zoOut.
#define STEP(SARG, M2WR, MXWR) do {                                           \
    const int  zS    = (SARG);                                                \
    const bool zsOK  = (zS >= 0 && zS < DD);                                  \
    const bool zeOK  = (zS >= 1 && zS <= DD);                                 \
    const int  zo    = zS - 2;                                                \
    const bool zoOut = (zS >= d0 + 2);                                        \
    float4 vr0, vr1, vr2, vr3, vr4, vr5, vr6, vr7;                            \
    float4 ic0, ic1, ic2, ic3, ot0, ot1, ot2, ot3;                            \
    /* ---- issue all global loads up front (16 coalesced float4/lane) ---- */\
    if (zsOK) {                                                               \
      const float* sb = imgL + (size_t)zS * HWS;                              \
      if (hOK0) vr0 = *(const float4*)(sb - 2*WD); else SET4(vr0, FINF);      \
      if (hOK1) vr1 = *(const float4*)(sb - 1*WD); else SET4(vr1, FINF);      \
      vr2 = *(const float4*)(sb);                                             \
      vr3 = *(const float4*)(sb + 1*WD);                                      \
      vr4 = *(const float4*)(sb + 2*WD);                                      \
      vr5 = *(const float4*)(sb + 3*WD);                                      \
      if (hOK6) vr6 = *(const float4*)(sb + 4*WD); else SET4(vr6, FINF);      \
      if (hOK7) vr7 = *(const float4*)(sb + 5*WD); else SET4(vr7, FINF);      \
    } else {                                                                  \
      SET4(vr0,FINF); SET4(vr1,FINF); SET4(vr2,FINF); SET4(vr3,FINF);         \
      SET4(vr4,FINF); SET4(vr5,FINF); SET4(vr6,FINF); SET4(vr7,FINF);         \
    }                                                                         \
    if (zoOut) {                                                              \
      const float* ib = imgL + (size_t)zo * HWS;                              \
      const float* ob = othL + (size_t)zo * HWS;                              \
      ic0 = *(const float4*)(ib);          ic1 = *(const float4*)(ib + WD);   \
      ic2 = *(const float4*)(ib + 2*WD);   ic3 = *(const float4*)(ib + 3*WD); \
      ot0 = *(const float4*)(ob);          ot1 = *(const float4*)(ob + WD);   \
      ot2 = *(const float4*)(ob + 2*WD);   ot3 = *(const float4*)(ob + 3*WD); \
    }                                                                         \
    float4 mw_p2, mw_p1, opn_p2, opn_p1;                                      \
    SET4(mw_p2,FINF); SET4(mw_p1,FINF); SET4(opn_p2,-FINF); SET4(opn_p1,-FINF);\
    _Pragma("unroll")                                                         \
    for (int rr = 0; rr < 8; ++rr) {                                          \
      float4 vv = (rr==0)?vr0:(rr==1)?vr1:(rr==2)?vr2:(rr==3)?vr3:            \
                  (rr==4)?vr4:(rr==5)?vr5:(rr==6)?vr6:vr7;                    \
      float lw = __shfl_up(vv.w, 1);   lw = (lane == 0)  ? FINF : lw;         \
      float rx = __shfl_down(vv.x, 1); rx = (lane == 63) ? FINF : rx;         \
      float4 mw;                                                              \
      mw.x = min3f(lw, vv.x, vv.y);   mw.y = min3f(vv.x, vv.y, vv.z);         \
      mw.z = min3f(vv.y, vv.z, vv.w); mw.w = min3f(vv.z, vv.w, rx);           \
      if (rr >= 2) {                                                          \
        const int ri = rr - 2;                                                \
        float4 m2c; MIN3V(m2c, mw_p2, mw_p1, mw);                             \
        float4 er;  MIN3V(er, m2c, m2_0[ri], m2_1[ri]);                       \
        M2WR[ri] = m2c;                                                       \
        if (!(zeOK && ehOK[ri])) SET4(er, -FINF);                             \
        float elw = __shfl_up(er.w, 1);   elw = (lane == 0)  ? -FINF : elw;   \
        float erx = __shfl_down(er.x, 1); erx = (lane == 63) ? -FINF : erx;   \
        float4 mx;                                                            \
        mx.x = max3f(elw, er.x, er.y);  mx.y = max3f(er.x, er.y, er.z);       \
        mx.z = max3f(er.y, er.z, er.w); mx.w = max3f(er.z, er.w, erx);        \
        float4 opn; MAX3V(opn, mx, mx_0[ri], mx_1[ri]);                       \
        MXWR[ri] = mx;                                                        \
        if (rr >= 4) {                                                        \
          float4 opened; MAX3V(opened, opn_p2, opn_p1, opn);                  \
          if (zoOut) {                                                        \
            float4 icv = (rr==4)?ic0:(rr==5)?ic1:(rr==6)?ic2:ic3;             \
            float4 otv = (rr==4)?ot0:(rr==5)?ot1:(rr==6)?ot2:ot3;             \
            float4 sk;                                                        \
            sk.x = fmaxf(icv.x - opened.x, 0.f);                              \
            sk.y = fmaxf(icv.y - opened.y, 0.f);                              \
            sk.z = fmaxf(icv.z - opened.z, 0.f);                              \
            sk.w = fmaxf(icv.w - opened.w, 0.f);                              \
            accN4.x += sk.x * otv.x; accN4.y += sk.y * otv.y;                 \
            accN4.z += sk.z * otv.z; accN4.w += sk.w * otv.w;                 \
            accD4.x += sk.x; accD4.y += sk.y;                                 \
            accD4.z += sk.z; accD4.w += sk.w;                                 \
          }                                                                   \
        }                                                                     \
        opn_p2 = opn_p1; opn_p1 = opn;                                        \
      }                                                                       \
      mw_p2 = mw_p1; mw_p1 = mw;                                              \
    }                                                                         \
  } while (0)

__global__ __launch_bounds__(NT, 2) void skel_reduce_kernel(
    const float* __restrict__ y_pred, const float* __restrict__ y_true,
    double* __restrict__ acc)
{
  __shared__ float red[2][4];

  const int tid  = threadIdx.x;
  const int wid  = tid >> 6;
  const int lane = tid & 63;
  const int gwv  = blockIdx.x * 4 + wid;     // 0..2047
  const int ht = gwv & 63;                   // 64 h-tiles of 4 rows
  const int dt = (gwv >> 6) & 7;             // 8 d-chunks of 16 slices
  const int v  = gwv >> 9;                   // role*2 + b (block-uniform)
  const int role = v >> 1, b = v & 1;

  const float* img = (role == 0 ? y_pred : y_true) + (size_t)b * VOLS;
  const float* oth = (role == 0 ? y_true : y_pred) + (size_t)b * VOLS;

  const int h0 = ht * 4, d0 = dt * DC;
  const float* imgL = img + (size_t)h0 * WD + 4 * lane;
  const float* othL = oth + (size_t)h0 * WD + 4 * lane;

  // h-border validity (wave-uniform)
  const bool hOK0 = (h0 - 2 >= 0), hOK1 = (h0 - 1 >= 0);
  const bool hOK6 = (h0 + 4 < HH), hOK7 = (h0 + 5 < HH);
  bool ehOK[6];
  #pragma unroll
  for (int i = 0; i < 6; ++i) ehOK[i] = ((unsigned)(h0 + i - 1) < HH);

  // D-direction ping-pong state: m2_0 = even slices, m2_1 = odd (same for mx)
  float4 m2_0[6], m2_1[6], mx_0[6], mx_1[6];
  #pragma unroll
  for (int i = 0; i < 6; ++i) {
    SET4(m2_0[i], FINF);  SET4(m2_1[i], FINF);
    SET4(mx_0[i], -FINF); SET4(mx_1[i], -FINF);
  }
  float4 accN4, accD4; SET4(accN4, 0.f); SET4(accD4, 0.f);

  // d0 is even, so slice parity is compile-time within the 2x-unrolled loop.
  for (int SS = d0 - 2; SS < d0 + DC + 2; SS += 2) {
    STEP(SS,     m2_0, mx_1);
    STEP(SS + 1, m2_1, mx_0);
  }

  float accN = accN4.x + accN4.y + accN4.z + accN4.w;
  float accD = accD4.x + accD4.y + accD4.z + accD4.w;
  #pragma unroll
  for (int off = 32; off > 0; off >>= 1) {
    accN += __shfl_down(accN, off);
    accD += __shfl_down(accD, off);
  }
  if (lane == 0) { red[0][wid] = accN; red[1][wid] = accD; }
  __syncthreads();
  if (tid == 0) {
    float n  = red[0][0] + red[0][1] + red[0][2] + red[0][3];
    float dn = red[1][0] + red[1][1] + red[1][2] + red[1][3];
    atomicAdd(&acc[v * 2 + 0], (double)n);
    atomicAdd(&acc[v * 2 + 1], (double)dn);
  }
}

__global__ void finalize_kernel(const double* __restrict__ acc,
                                float* __restrict__ out)
{
  const double smooth = 1e-5;
  double cl[2];
  for (int b = 0; b < 2; ++b) {
    double tprec = acc[(0 * 2 + b) * 2 + 0] / (acc[(0 * 2 + b) * 2 + 1] + smooth);
    double tsens = acc[(1 * 2 + b) * 2 + 0] / (acc[(1 * 2 + b) * 2 + 1] + smooth);
    cl[b] = 2.0 * tprec * tsens / (tprec + tsens + smooth);
  }
  out[0] = (float)(1.0 - 0.5 * (cl[0] + cl[1]));
}

extern "C" void kernel_launch(void* const* d_in, const int* in_sizes, int n_in,
                              void* d_out, int out_size, void* d_ws, size_t ws_size,
                              hipStream_t stream) {
  const float* y_pred = (const float*)d_in[0];
  const float* y_true = (const float*)d_in[1];
  double* acc = (double*)d_ws;
  hipMemsetAsync(d_ws, 0, 8 * sizeof(double), stream);
  // 2048 waves: 4 role-vols x 8 d-chunks x 64 h-tiles -> 512 blocks x 4 waves
  skel_reduce_kernel<<<dim3(512), dim3(NT), 0, stream>>>(y_pred, y_true, acc);
  finalize_kernel<<<dim3(1), dim3(1), 0, stream>>>(acc, (float*)d_out);
}